// Round 1
// baseline (916.438 us; speedup 1.0000x reference)
//
#include <hip/hip_runtime.h>
#include <hip/hip_bf16.h>
#include <stdint.h>

// Problem constants
#define NUM_CB   8
#define CB_BITS  11      // id >> 11 = codebook
#define DIM      16
#define HS       2048
#define NTOK     16384

// GEMM tiling
#define BM 128
#define BN 128
#define BK 32
#define MAXT 160         // >= sum ceil(cnt_k/128) <= 16384/128 + 8 = 136
#define PADCAP (136*BM)  // 17408 padded rows max

// Workspace layout (bytes)
#define OFF_CNT    0u          // 8 x u32
#define OFF_CUR    32u         // 8 x u32
#define OFF_NT     64u         // 1 x u32
#define OFF_GS     96u         // 8 x u32 (padded group start rows)
#define OFF_TCB    128u        // MAXT x u32
#define OFF_TROW   768u        // MAXT x u32
#define OFF_TVAL   1408u       // MAXT x u32
#define OFF_PERM   2048u       // PADCAP x u32 -> ends 71680
#define OFF_H      71680u      // PADCAP*HS bf16 = 71303168 B
#define OFF_W2T    71374848u   // 8*HS*HS bf16 = 67108864 B
#define WS_NEED    138483712u

typedef __attribute__((ext_vector_type(8))) short s16x8;
typedef __attribute__((ext_vector_type(4))) float f32x4;

__device__ __forceinline__ void load_lds16(const void* g, void* l) {
    __builtin_amdgcn_global_load_lds(
        (const __attribute__((address_space(1))) uint32_t*)g,
        (__attribute__((address_space(3))) uint32_t*)l, 16, 0, 0);
}

extern "C" __global__ void k_count(const int* __restrict__ ids, uint32_t* __restrict__ cnt) {
    int t = blockIdx.x * blockDim.x + threadIdx.x;
    if (t < NTOK) atomicAdd(&cnt[(uint32_t)ids[t] >> CB_BITS], 1u);
}

extern "C" __global__ void k_plan(const uint32_t* __restrict__ cnt, uint32_t* __restrict__ numT,
                                  uint32_t* __restrict__ tcb, uint32_t* __restrict__ trow,
                                  uint32_t* __restrict__ tval, uint32_t* __restrict__ gstart) {
    if (threadIdx.x != 0 || blockIdx.x != 0) return;
    uint32_t ps = 0, nt = 0;
    for (int k = 0; k < NUM_CB; ++k) {
        gstart[k] = ps;
        uint32_t c = cnt[k];
        uint32_t tiles = (c + BM - 1) / BM;
        for (uint32_t m = 0; m < tiles; ++m) {
            tcb[nt] = (uint32_t)k;
            trow[nt] = ps + m * BM;
            uint32_t rem = c - m * BM;
            tval[nt] = rem < BM ? rem : BM;
            ++nt;
        }
        ps += tiles * BM;
    }
    *numT = nt;
}

extern "C" __global__ void k_assign(const int* __restrict__ ids, const uint32_t* __restrict__ gstart,
                                    uint32_t* __restrict__ cur, uint32_t* __restrict__ perm) {
    int t = blockIdx.x * blockDim.x + threadIdx.x;
    if (t < NTOK) {
        int cb = (uint32_t)ids[t] >> CB_BITS;
        uint32_t p = atomicAdd(&cur[cb], 1u);
        perm[gstart[cb] + p] = (uint32_t)t;
    }
}

// H[row] = gelu(e(row) @ W1[cb] + b1[cb]) in bf16, codebook-sorted + 128-padded rows.
extern "C" __global__ void k_hbuild(const int* __restrict__ ids, const float* __restrict__ emb,
                                    const float* __restrict__ W1, const float* __restrict__ b1,
                                    const uint32_t* __restrict__ numT, const uint32_t* __restrict__ tcb,
                                    const uint32_t* __restrict__ trow, const uint32_t* __restrict__ tval,
                                    const uint32_t* __restrict__ perm, __hip_bfloat16* __restrict__ H) {
    if (blockIdx.x >= *numT) return;
    const int cb = (int)tcb[blockIdx.x];
    const int row0 = (int)trow[blockIdx.x];
    const int valid = (int)tval[blockIdx.x];
    const int tid = threadIdx.x;

    __shared__ float es[BM][DIM];     // 8 KB
    __shared__ float w1s[DIM][256];   // 16 KB
    __shared__ float b1s[256];
    __shared__ int   rid[BM];

    if (tid < BM) rid[tid] = (tid < valid) ? ids[perm[row0 + tid]] : -1;
    __syncthreads();
    for (int idx = tid; idx < BM * DIM; idx += 256) {
        int r = idx >> 4, d = idx & 15;
        int id = rid[r];
        es[r][d] = (id >= 0) ? emb[(size_t)id * DIM + d] : 0.f;
    }
    __syncthreads();

    const float* W1k = W1 + (size_t)cb * DIM * HS;
    const float* b1k = b1 + (size_t)cb * HS;

    for (int ch = 0; ch < HS / 256; ++ch) {
        for (int idx = tid; idx < DIM * 256; idx += 256) {
            int d = idx >> 8, c = idx & 255;
            w1s[d][c] = W1k[(size_t)d * HS + ch * 256 + c];
        }
        b1s[tid] = b1k[ch * 256 + tid];
        __syncthreads();

        float w[DIM];
        #pragma unroll
        for (int d = 0; d < DIM; ++d) w[d] = w1s[d][tid];
        const float bb = b1s[tid];

        for (int r = 0; r < BM; ++r) {
            const float4 e0 = *(const float4*)&es[r][0];
            const float4 e1 = *(const float4*)&es[r][4];
            const float4 e2 = *(const float4*)&es[r][8];
            const float4 e3 = *(const float4*)&es[r][12];
            float acc = bb;
            acc += e0.x*w[0] + e0.y*w[1] + e0.z*w[2] + e0.w*w[3];
            acc += e1.x*w[4] + e1.y*w[5] + e1.z*w[6] + e1.w*w[7];
            acc += e2.x*w[8] + e2.y*w[9] + e2.z*w[10] + e2.w*w[11];
            acc += e3.x*w[12] + e3.y*w[13] + e3.z*w[14] + e3.w*w[15];
            float g = 0.5f * acc * (1.f + erff(acc * 0.70710678118f));
            H[(size_t)(row0 + r) * HS + ch * 256 + tid] = __float2bfloat16(g);
        }
        __syncthreads();
    }
}

// W2 [cb][k][n] f32 -> W2T [cb][n][k] bf16 (so GEMM B-staging is linear in k)
extern "C" __global__ void k_w2t(const float* __restrict__ W2, __hip_bfloat16* __restrict__ W2T) {
    __shared__ float s[64][65];
    const int k0 = blockIdx.x * 64, n0 = blockIdx.y * 64, cb = blockIdx.z;
    const int tid = threadIdx.x;
    const float* src = W2 + ((size_t)cb << 22);
    #pragma unroll
    for (int i = 0; i < 16; ++i) {
        int idx = i * 256 + tid;
        int kl = idx >> 6, nl = idx & 63;
        s[kl][nl] = src[(size_t)(k0 + kl) * HS + n0 + nl];
    }
    __syncthreads();
    __hip_bfloat16* dst = W2T + ((size_t)cb << 22);
    #pragma unroll
    for (int i = 0; i < 16; ++i) {
        int idx = i * 256 + tid;
        int nl = idx >> 6, kl = idx & 63;
        dst[(size_t)(n0 + nl) * HS + k0 + kl] = __float2bfloat16(s[kl][nl]);
    }
}

// Grouped GEMM: out[perm[r]] = H[r] @ W2T[cb]^T + b2[cb]
// LDS layout per operand tile: [4 kchunks][128 rows][8 bf16] -> conflict-free ds_read_b128.
extern "C" __global__ void __launch_bounds__(256) k_gemm(
    const __hip_bfloat16* __restrict__ Hb, const __hip_bfloat16* __restrict__ W2Tb,
    const float* __restrict__ b2, const uint32_t* __restrict__ numT,
    const uint32_t* __restrict__ tcb, const uint32_t* __restrict__ trow,
    const uint32_t* __restrict__ tval, const uint32_t* __restrict__ perm,
    float* __restrict__ out)
{
    const int mslot = blockIdx.y;
    if (mslot >= (int)*numT) return;
    const int cb = (int)tcb[mslot];
    const int row0 = (int)trow[mslot];
    const int valid = (int)tval[mslot];
    const int n0 = blockIdx.x * BN;

    const int tid = threadIdx.x;
    const int lane = tid & 63, wave = tid >> 6;
    const int wm = wave >> 1, wn = wave & 1;

    __shared__ __align__(16) unsigned short As[2][4096];  // 8KB x2
    __shared__ __align__(16) unsigned short Bs[2][4096];

    const unsigned short* H = (const unsigned short*)Hb;
    const unsigned short* W2 = (const unsigned short*)W2Tb;

    const int idx0 = tid, idx1 = 256 + tid;
    const unsigned short* gA0 = H + (size_t)(row0 + (idx0 & 127)) * HS + (idx0 >> 7) * 8;
    const unsigned short* gA1 = H + (size_t)(row0 + (idx1 & 127)) * HS + (idx1 >> 7) * 8;
    const unsigned short* gB0 = W2 + ((size_t)cb * HS + n0 + (idx0 & 127)) * HS + (idx0 >> 7) * 8;
    const unsigned short* gB1 = W2 + ((size_t)cb * HS + n0 + (idx1 & 127)) * HS + (idx1 >> 7) * 8;

    const uint32_t ls0 = (uint32_t)__builtin_amdgcn_readfirstlane(wave * 512);
    const uint32_t ls1 = (uint32_t)__builtin_amdgcn_readfirstlane(2048 + wave * 512);

    f32x4 acc[4][4];
    #pragma unroll
    for (int i = 0; i < 4; ++i)
        #pragma unroll
        for (int j = 0; j < 4; ++j) acc[i][j] = (f32x4){0.f, 0.f, 0.f, 0.f};

    // prologue: stage k-step 0 into buffer 0
    load_lds16(gA0, &As[0][ls0]);
    load_lds16(gA1, &As[0][ls1]);
    load_lds16(gB0, &Bs[0][ls0]);
    load_lds16(gB1, &Bs[0][ls1]);
    __syncthreads();

    const int c = lane >> 4, r = lane & 15;
    uint32_t aoff[4], boff[4];
    #pragma unroll
    for (int f = 0; f < 4; ++f) {
        aoff[f] = c * 1024 + (wm * 64 + f * 16 + r) * 8;
        boff[f] = c * 1024 + (wn * 64 + f * 16 + r) * 8;
    }

    const int NK = HS / BK;  // 64
    for (int kk = 0; kk < NK; ++kk) {
        const int curb = kk & 1;
        if (kk + 1 < NK) {
            const int nxt = curb ^ 1;
            const size_t kadv = (size_t)(kk + 1) * BK;
            load_lds16(gA0 + kadv, &As[nxt][ls0]);
            load_lds16(gA1 + kadv, &As[nxt][ls1]);
            load_lds16(gB0 + kadv, &Bs[nxt][ls0]);
            load_lds16(gB1 + kadv, &Bs[nxt][ls1]);
        }
        s16x8 a[4], b[4];
        #pragma unroll
        for (int f = 0; f < 4; ++f) a[f] = *(const s16x8*)&As[curb][aoff[f]];
        #pragma unroll
        for (int f = 0; f < 4; ++f) b[f] = *(const s16x8*)&Bs[curb][boff[f]];
        #pragma unroll
        for (int mf = 0; mf < 4; ++mf)
            #pragma unroll
            for (int nf = 0; nf < 4; ++nf)
                acc[mf][nf] = __builtin_amdgcn_mfma_f32_16x16x32_bf16(a[mf], b[nf], acc[mf][nf], 0, 0, 0);
        __syncthreads();
    }

    // epilogue: + b2, scatter rows through perm
    const float* b2k = b2 + (size_t)cb * HS;
    const int ncol = n0 + wn * 64 + (lane & 15);
    float bias[4];
    #pragma unroll
    for (int nf = 0; nf < 4; ++nf) bias[nf] = b2k[ncol + nf * 16];

    #pragma unroll
    for (int mf = 0; mf < 4; ++mf) {
        #pragma unroll
        for (int jj = 0; jj < 4; ++jj) {
            const int m = wm * 64 + mf * 16 + (lane >> 4) * 4 + jj;
            if (m < valid) {
                const int orow = (int)perm[row0 + m];
                float* op = out + (size_t)orow * HS;
                #pragma unroll
                for (int nf = 0; nf < 4; ++nf)
                    op[ncol + nf * 16] = acc[mf][nf][jj] + bias[nf];
            }
        }
    }
}

extern "C" void kernel_launch(void* const* d_in, const int* in_sizes, int n_in,
                              void* d_out, int out_size, void* d_ws, size_t ws_size,
                              hipStream_t stream) {
    const int*   ids = (const int*)d_in[0];
    const float* emb = (const float*)d_in[1];
    const float* W1  = (const float*)d_in[2];
    const float* b1  = (const float*)d_in[3];
    const float* W2  = (const float*)d_in[4];
    const float* b2  = (const float*)d_in[5];
    float* out = (float*)d_out;

    if (ws_size < (size_t)WS_NEED) return;  // loud failure instead of corruption

    char* ws = (char*)d_ws;
    uint32_t* cnt    = (uint32_t*)(ws + OFF_CNT);
    uint32_t* cur    = (uint32_t*)(ws + OFF_CUR);
    uint32_t* numT   = (uint32_t*)(ws + OFF_NT);
    uint32_t* gstart = (uint32_t*)(ws + OFF_GS);
    uint32_t* tcb    = (uint32_t*)(ws + OFF_TCB);
    uint32_t* trow   = (uint32_t*)(ws + OFF_TROW);
    uint32_t* tval   = (uint32_t*)(ws + OFF_TVAL);
    uint32_t* perm   = (uint32_t*)(ws + OFF_PERM);
    __hip_bfloat16* Hbf  = (__hip_bfloat16*)(ws + OFF_H);
    __hip_bfloat16* W2Tb = (__hip_bfloat16*)(ws + OFF_W2T);

    hipMemsetAsync(ws, 0, 64, stream);  // cnt + cur

    k_count <<<NTOK / 256, 256, 0, stream>>>(ids, cnt);
    k_plan  <<<1, 1, 0, stream>>>(cnt, numT, tcb, trow, tval, gstart);
    k_assign<<<NTOK / 256, 256, 0, stream>>>(ids, gstart, cur, perm);
    k_w2t   <<<dim3(32, 32, 8), 256, 0, stream>>>(W2, W2Tb);
    k_hbuild<<<MAXT, 256, 0, stream>>>(ids, emb, W1, b1, numT, tcb, trow, tval, perm, Hbf);
    k_gemm  <<<dim3(HS / BN, MAXT), 256, 0, stream>>>(Hbf, W2Tb, b2, numT, tcb, trow, tval, perm, out);
}

// Round 2
// 619.284 us; speedup vs baseline: 1.4798x; 1.4798x over previous
//
#include <hip/hip_runtime.h>
#include <hip/hip_bf16.h>
#include <stdint.h>

// Problem constants
#define NUM_CB   8
#define CB_BITS  11      // id >> 11 = codebook
#define DIM      16
#define HS       2048
#define NTOK     16384

// GEMM tiling
#define BM 128
#define BN 128
#define BK 32
#define MAXT 160         // >= sum ceil(cnt_k/128) <= 16384/128 + 8 = 136
#define PADCAP (136*BM)  // 17408 padded rows max

// Workspace layout (bytes)
#define OFF_CNT    0u          // 8 x u32 (unused now, kept for layout stability)
#define OFF_CUR    32u         // 8 x u32
#define OFF_NT     64u         // 1 x u32
#define OFF_GS     96u         // 8 x u32 (padded group start rows)
#define OFF_TCB    128u        // MAXT x u32
#define OFF_TROW   768u        // MAXT x u32
#define OFF_TVAL   1408u       // MAXT x u32
#define OFF_PERM   2048u       // PADCAP x u32 -> ends 71680
#define OFF_H      71680u      // PADCAP*HS bf16 = 71303168 B
#define OFF_W2T    71374848u   // 8*HS*HS bf16 = 67108864 B
#define WS_NEED    138483712u

typedef __attribute__((ext_vector_type(8))) short s16x8;
typedef __attribute__((ext_vector_type(4))) float f32x4;

__device__ __forceinline__ void load_lds16(const void* g, void* l) {
    __builtin_amdgcn_global_load_lds(
        (const __attribute__((address_space(1))) uint32_t*)g,
        (__attribute__((address_space(3))) uint32_t*)l, 16, 0, 0);
}

// One block (1024 threads): LDS histogram of codebooks + serial tile plan in LDS
// + parallel write-out. Replaces k_count + k_plan + the global memset.
extern "C" __global__ void k_countplan(const int* __restrict__ ids,
                                       uint32_t* __restrict__ cur, uint32_t* __restrict__ numT,
                                       uint32_t* __restrict__ tcb, uint32_t* __restrict__ trow,
                                       uint32_t* __restrict__ tval, uint32_t* __restrict__ gstart) {
    __shared__ uint32_t hist[NUM_CB];
    __shared__ uint32_t s_tcb[MAXT], s_trow[MAXT], s_tval[MAXT];
    __shared__ uint32_t s_gs[NUM_CB], s_nt;
    const int tid = threadIdx.x;
    if (tid < NUM_CB) { hist[tid] = 0; cur[tid] = 0; }
    __syncthreads();
    for (int i = tid; i < NTOK; i += 1024)
        atomicAdd(&hist[(uint32_t)ids[i] >> CB_BITS], 1u);
    __syncthreads();
    if (tid == 0) {
        uint32_t ps = 0, nt = 0;
        for (int k = 0; k < NUM_CB; ++k) {
            s_gs[k] = ps;
            uint32_t c = hist[k];
            uint32_t tiles = (c + BM - 1) / BM;
            for (uint32_t m = 0; m < tiles; ++m) {
                s_tcb[nt] = (uint32_t)k;
                s_trow[nt] = ps + m * BM;
                uint32_t rem = c - m * BM;
                s_tval[nt] = rem < BM ? rem : BM;
                ++nt;
            }
            ps += tiles * BM;
        }
        s_nt = nt;
    }
    __syncthreads();
    const uint32_t nt = s_nt;
    if (tid < MAXT) {
        tcb[tid]  = (tid < (int)nt) ? s_tcb[tid] : 0u;
        trow[tid] = (tid < (int)nt) ? s_trow[tid] : 0u;
        tval[tid] = (tid < (int)nt) ? s_tval[tid] : 0u;
    }
    if (tid < NUM_CB) gstart[tid] = s_gs[tid];
    if (tid == 0) *numT = nt;
}

// Per-block LDS histogram -> claim contiguous ranges with 8 global atomics ->
// distribute local ranks via LDS atomics. Order within a group is irrelevant.
extern "C" __global__ void k_assign(const int* __restrict__ ids, const uint32_t* __restrict__ gstart,
                                    uint32_t* __restrict__ cur, uint32_t* __restrict__ perm) {
    __shared__ uint32_t lh[NUM_CB], lbase[NUM_CB];
    const int tid = threadIdx.x;
    const int t = blockIdx.x * 256 + tid;
    if (tid < NUM_CB) lh[tid] = 0;
    __syncthreads();
    const int cb = (uint32_t)ids[t] >> CB_BITS;
    atomicAdd(&lh[cb], 1u);
    __syncthreads();
    if (tid < NUM_CB) {
        lbase[tid] = lh[tid] ? atomicAdd(&cur[tid], lh[tid]) : 0u;
        lh[tid] = 0;
    }
    __syncthreads();
    const uint32_t r = atomicAdd(&lh[cb], 1u);
    perm[gstart[cb] + lbase[cb] + r] = (uint32_t)t;
}

// H[row, col0:col0+256] = gelu(e(row) @ W1[cb] + b1[cb]), grid (MAXT, 8).
extern "C" __global__ void k_hbuild(const int* __restrict__ ids, const float* __restrict__ emb,
                                    const float* __restrict__ W1, const float* __restrict__ b1,
                                    const uint32_t* __restrict__ numT, const uint32_t* __restrict__ tcb,
                                    const uint32_t* __restrict__ trow, const uint32_t* __restrict__ tval,
                                    const uint32_t* __restrict__ perm, __hip_bfloat16* __restrict__ H) {
    if (blockIdx.x >= *numT) return;
    const int cb = (int)tcb[blockIdx.x];
    const int row0 = (int)trow[blockIdx.x];
    const int valid = (int)tval[blockIdx.x];
    const int col0 = blockIdx.y * 256;
    const int tid = threadIdx.x;

    __shared__ float es[BM][DIM];     // 8 KB
    __shared__ float w1s[DIM][256];   // 16 KB
    __shared__ int   rid[BM];

    if (tid < BM) rid[tid] = (tid < valid) ? ids[perm[row0 + tid]] : 0;
    __syncthreads();
    for (int idx = tid; idx < BM * DIM; idx += 256) {
        int r = idx >> 4, d = idx & 15;
        es[r][d] = emb[(size_t)rid[r] * DIM + d];
    }
    const float* W1k = W1 + (size_t)cb * DIM * HS + col0;
    for (int idx = tid; idx < DIM * 256; idx += 256) {
        int d = idx >> 8, c = idx & 255;
        w1s[d][c] = W1k[(size_t)d * HS + c];
    }
    __syncthreads();

    float w[DIM];
    #pragma unroll
    for (int d = 0; d < DIM; ++d) w[d] = w1s[d][tid];
    const float bb = b1[(size_t)cb * HS + col0 + tid];
    __hip_bfloat16* Hc = H + (size_t)row0 * HS + col0 + tid;

    for (int r = 0; r < BM; ++r) {
        const float4 e0 = *(const float4*)&es[r][0];
        const float4 e1 = *(const float4*)&es[r][4];
        const float4 e2 = *(const float4*)&es[r][8];
        const float4 e3 = *(const float4*)&es[r][12];
        float acc = bb;
        acc += e0.x*w[0] + e0.y*w[1] + e0.z*w[2] + e0.w*w[3];
        acc += e1.x*w[4] + e1.y*w[5] + e1.z*w[6] + e1.w*w[7];
        acc += e2.x*w[8] + e2.y*w[9] + e2.z*w[10] + e2.w*w[11];
        acc += e3.x*w[12] + e3.y*w[13] + e3.z*w[14] + e3.w*w[15];
        float g = 0.5f * acc * (1.f + erff(acc * 0.70710678118f));
        Hc[(size_t)r * HS] = __float2bfloat16(g);
    }
}

// W2 [cb][k][n] f32 -> W2T [cb][n][k] bf16 (so GEMM B-staging is linear in k)
extern "C" __global__ void k_w2t(const float* __restrict__ W2, __hip_bfloat16* __restrict__ W2T) {
    __shared__ float s[64][65];
    const int k0 = blockIdx.x * 64, n0 = blockIdx.y * 64, cb = blockIdx.z;
    const int tid = threadIdx.x;
    const float* src = W2 + ((size_t)cb << 22);
    #pragma unroll
    for (int i = 0; i < 16; ++i) {
        int idx = i * 256 + tid;
        int kl = idx >> 6, nl = idx & 63;
        s[kl][nl] = src[(size_t)(k0 + kl) * HS + n0 + nl];
    }
    __syncthreads();
    __hip_bfloat16* dst = W2T + ((size_t)cb << 22);
    #pragma unroll
    for (int i = 0; i < 16; ++i) {
        int idx = i * 256 + tid;
        int nl = idx >> 6, kl = idx & 63;
        dst[(size_t)(n0 + nl) * HS + k0 + kl] = __float2bfloat16(s[kl][nl]);
    }
}

// Grouped GEMM: out[perm[r]] = H[r] @ W2T[cb]^T + b2[cb]
// LDS layout per operand tile: [4 kchunks][128 rows][8 bf16] -> conflict-free ds_read_b128.
extern "C" __global__ void __launch_bounds__(256, 4) k_gemm(
    const __hip_bfloat16* __restrict__ Hb, const __hip_bfloat16* __restrict__ W2Tb,
    const float* __restrict__ b2, const uint32_t* __restrict__ numT,
    const uint32_t* __restrict__ tcb, const uint32_t* __restrict__ trow,
    const uint32_t* __restrict__ tval, const uint32_t* __restrict__ perm,
    float* __restrict__ out)
{
    const int mslot = blockIdx.y;
    if (mslot >= (int)*numT) return;
    const int cb = (int)tcb[mslot];
    const int row0 = (int)trow[mslot];
    const int valid = (int)tval[mslot];
    const int n0 = blockIdx.x * BN;

    const int tid = threadIdx.x;
    const int lane = tid & 63, wave = tid >> 6;
    const int wm = wave >> 1, wn = wave & 1;

    __shared__ __align__(16) unsigned short As[2][4096];  // 8KB x2
    __shared__ __align__(16) unsigned short Bs[2][4096];

    const unsigned short* H = (const unsigned short*)Hb;
    const unsigned short* W2 = (const unsigned short*)W2Tb;

    const int idx0 = tid, idx1 = 256 + tid;
    const unsigned short* gA0 = H + (size_t)(row0 + (idx0 & 127)) * HS + (idx0 >> 7) * 8;
    const unsigned short* gA1 = H + (size_t)(row0 + (idx1 & 127)) * HS + (idx1 >> 7) * 8;
    const unsigned short* gB0 = W2 + ((size_t)cb * HS + n0 + (idx0 & 127)) * HS + (idx0 >> 7) * 8;
    const unsigned short* gB1 = W2 + ((size_t)cb * HS + n0 + (idx1 & 127)) * HS + (idx1 >> 7) * 8;

    const uint32_t ls0 = (uint32_t)__builtin_amdgcn_readfirstlane(wave * 512);
    const uint32_t ls1 = (uint32_t)__builtin_amdgcn_readfirstlane(2048 + wave * 512);

    f32x4 acc[4][4];
    #pragma unroll
    for (int i = 0; i < 4; ++i)
        #pragma unroll
        for (int j = 0; j < 4; ++j) acc[i][j] = (f32x4){0.f, 0.f, 0.f, 0.f};

    // prologue: stage k-step 0 into buffer 0
    load_lds16(gA0, &As[0][ls0]);
    load_lds16(gA1, &As[0][ls1]);
    load_lds16(gB0, &Bs[0][ls0]);
    load_lds16(gB1, &Bs[0][ls1]);
    __syncthreads();

    const int c = lane >> 4, r = lane & 15;
    uint32_t aoff[4], boff[4];
    #pragma unroll
    for (int f = 0; f < 4; ++f) {
        aoff[f] = c * 1024 + (wm * 64 + f * 16 + r) * 8;
        boff[f] = c * 1024 + (wn * 64 + f * 16 + r) * 8;
    }

    const int NK = HS / BK;  // 64
    for (int kk = 0; kk < NK; ++kk) {
        const int curb = kk & 1;
        if (kk + 1 < NK) {
            const int nxt = curb ^ 1;
            const size_t kadv = (size_t)(kk + 1) * BK;
            load_lds16(gA0 + kadv, &As[nxt][ls0]);
            load_lds16(gA1 + kadv, &As[nxt][ls1]);
            load_lds16(gB0 + kadv, &Bs[nxt][ls0]);
            load_lds16(gB1 + kadv, &Bs[nxt][ls1]);
        }
        s16x8 a[4], b[4];
        #pragma unroll
        for (int f = 0; f < 4; ++f) a[f] = *(const s16x8*)&As[curb][aoff[f]];
        #pragma unroll
        for (int f = 0; f < 4; ++f) b[f] = *(const s16x8*)&Bs[curb][boff[f]];
        #pragma unroll
        for (int mf = 0; mf < 4; ++mf)
            #pragma unroll
            for (int nf = 0; nf < 4; ++nf)
                acc[mf][nf] = __builtin_amdgcn_mfma_f32_16x16x32_bf16(a[mf], b[nf], acc[mf][nf], 0, 0, 0);
        __syncthreads();
    }

    // epilogue: + b2, scatter rows through perm
    const float* b2k = b2 + (size_t)cb * HS;
    const int ncol = n0 + wn * 64 + (lane & 15);
    float bias[4];
    #pragma unroll
    for (int nf = 0; nf < 4; ++nf) bias[nf] = b2k[ncol + nf * 16];

    #pragma unroll
    for (int mf = 0; mf < 4; ++mf) {
        #pragma unroll
        for (int jj = 0; jj < 4; ++jj) {
            const int m = wm * 64 + mf * 16 + (lane >> 4) * 4 + jj;
            if (m < valid) {
                const int orow = (int)perm[row0 + m];
                float* op = out + (size_t)orow * HS;
                #pragma unroll
                for (int nf = 0; nf < 4; ++nf)
                    op[ncol + nf * 16] = acc[mf][nf][jj] + bias[nf];
            }
        }
    }
}

extern "C" void kernel_launch(void* const* d_in, const int* in_sizes, int n_in,
                              void* d_out, int out_size, void* d_ws, size_t ws_size,
                              hipStream_t stream) {
    const int*   ids = (const int*)d_in[0];
    const float* emb = (const float*)d_in[1];
    const float* W1  = (const float*)d_in[2];
    const float* b1  = (const float*)d_in[3];
    const float* W2  = (const float*)d_in[4];
    const float* b2  = (const float*)d_in[5];
    float* out = (float*)d_out;

    if (ws_size < (size_t)WS_NEED) return;  // loud failure instead of corruption

    char* ws = (char*)d_ws;
    uint32_t* cur    = (uint32_t*)(ws + OFF_CUR);
    uint32_t* numT   = (uint32_t*)(ws + OFF_NT);
    uint32_t* gstart = (uint32_t*)(ws + OFF_GS);
    uint32_t* tcb    = (uint32_t*)(ws + OFF_TCB);
    uint32_t* trow   = (uint32_t*)(ws + OFF_TROW);
    uint32_t* tval   = (uint32_t*)(ws + OFF_TVAL);
    uint32_t* perm   = (uint32_t*)(ws + OFF_PERM);
    __hip_bfloat16* Hbf  = (__hip_bfloat16*)(ws + OFF_H);
    __hip_bfloat16* W2Tb = (__hip_bfloat16*)(ws + OFF_W2T);

    k_countplan<<<1, 1024, 0, stream>>>(ids, cur, numT, tcb, trow, tval, gstart);
    k_assign   <<<NTOK / 256, 256, 0, stream>>>(ids, gstart, cur, perm);
    k_w2t      <<<dim3(32, 32, 8), 256, 0, stream>>>(W2, W2Tb);
    k_hbuild   <<<dim3(MAXT, 8), 256, 0, stream>>>(ids, emb, W1, b1, numT, tcb, trow, tval, perm, Hbf);
    k_gemm     <<<dim3(HS / BN, MAXT), 256, 0, stream>>>(Hbf, W2Tb, b2, numT, tcb, trow, tval, perm, out);
}